// Round 5
// baseline (248.723 us; speedup 1.0000x reference)
//
#include <hip/hip_runtime.h>

typedef __bf16 bf16_t;
typedef __bf16 bf16x8 __attribute__((ext_vector_type(8)));
typedef __bf16 bf16x4 __attribute__((ext_vector_type(4)));
typedef float  f32x4  __attribute__((ext_vector_type(4)));

// ---------------------------------------------------------------------------
// Workspace layout (floats unless noted):
//   A  : [4096][256] f32   (xf @ W1[0:26])                       4 MB
//   C  : [4096][256] f32   (xf @ W1[26:52] + qst @ W1[52:180] + b1)  4 MB
//   Wt : 3 x [256][256] bf16 in MFMA A-fragment layout:
//        [mat][tile16(no>>4)][ks(k>>5)][lane(q*16+r)][e]  where
//        no = n-row, q=(k>>3)&3, r=no&15, e=k&7.  Per-(tile,ks) wave load
//        is one coalesced 1 KB transaction.                      384 KB
//   xg : [64][256] f32     (pair-summed g output)                64 KB
//
// h in LDS uses the matching B-fragment-linear layout:
//   h[chunk = mt*8+ks][lane = q*16+r][e]  <->  h[m = mt*16+r][k = ks*32+q*8+e]
// so ALL LDS reads/writes are lane-contiguous -> zero bank conflicts by
// construction.
//
// Round 5: keep r4's operand split (4 wf global + 8 hf LDS -> 32 MFMA/ks)
// and add an explicit one-ks-deep software pipeline: double-buffered wf/hf,
// next-ks loads issued BEFORE the current MFMA cluster.  r4 measured
// MfmaUtil 31% with HBM idle and conflicts trivial: the serializer is the
// per-ks load latency chain (~200cy global + ~120cy LDS) exposed at
// 2 barrier-locked waves/SIMD.  Registers: acc 128 AGPR + wf 32 + hf 64
// + addr ~10 = ~234 of 256 -> fits without spill.
// ---------------------------------------------------------------------------

// ---------------- prep: A, C, weight fragment-relayout, zero xg -------------
__global__ __launch_bounds__(256) void rn_prep_kernel(
    const float* __restrict__ x, const float* __restrict__ qst,
    const float* __restrict__ g1w, const float* __restrict__ g1b,
    const float* __restrict__ g2w, const float* __restrict__ g3w,
    const float* __restrict__ g4w,
    float* __restrict__ A, float* __restrict__ C,
    bf16_t* __restrict__ Wt, float* __restrict__ xg)
{
  __shared__ float T[64][65];   // transpose tile (only used by that branch)
  int blk = blockIdx.x;
  int n   = threadIdx.x;  // 0..255
  if (blk < 256) {
    // block = (b, jg): rows jg*16 .. jg*16+15 of batch b; thread = output col n
    int b  = blk >> 2;
    int jg = (blk & 3) * 16;
    float accQ = g1b[n];
    const float* qb = qst + b * 128;
    #pragma unroll 8
    for (int qi = 0; qi < 128; ++qi)
      accQ += qb[qi] * g1w[(52 + qi) * 256 + n];

    float w24 = g1w[24 * 256 + n], w25 = g1w[25 * 256 + n];
    float w50 = g1w[50 * 256 + n], w51 = g1w[51 * 256 + n];
    float accA[16], accC[16];
    #pragma unroll
    for (int t = 0; t < 16; ++t) {
      int j = jg + t;
      // faithful to (a/d - d/2)/(d/2.0) float arithmetic, d=8 (exact pow2 ops)
      float cx = ((float)j * 0.125f - 4.0f) * 0.25f;
      float cy = ((float)(j & 7) - 4.0f) * 0.25f;
      accA[t] = cx * w24 + cy * w25;
      accC[t] = accQ + cx * w50 + cy * w51;
    }
    for (int c = 0; c < 24; ++c) {
      float wa = g1w[c * 256 + n];
      float wc = g1w[(26 + c) * 256 + n];
      const float* xc = x + (b * 24 + c) * 64 + jg;
      #pragma unroll
      for (int t = 0; t < 16; ++t) {
        float xv = xc[t];   // uniform per thread -> scalar load
        accA[t] += xv * wa;
        accC[t] += xv * wc;
      }
    }
    #pragma unroll
    for (int t = 0; t < 16; ++t) {
      A[(b * 64 + jg + t) * 256 + n] = accA[t];
      C[(b * 64 + jg + t) * 256 + n] = accC[t];
    }
  } else if (blk < 256 + 48) {
    // LDS-tiled transpose: g2/g3/g4 [in(k)][out(no)] f32 -> bf16 fragment
    // layout: element (no,k) -> [(no>>4)*8 + (k>>5)][((k>>3)&3)*16 + (no&15)][k&7]
    int t   = blk - 256;
    int mat = t >> 4;                 // 0..2
    int tl  = t & 15;                 // 4x4 tiles of 64x64
    int kt  = (tl & 3) * 64;
    int nt_ = (tl >> 2) * 64;
    const float* W = (mat == 0) ? g2w : (mat == 1 ? g3w : g4w);
    int lane = n & 63, w = n >> 6;
    #pragma unroll
    for (int it = 0; it < 16; ++it) {
      int kl = w * 16 + it;
      T[kl][lane] = W[(kt + kl) * 256 + nt_ + lane];   // coalesced 256B/wave
    }
    __syncthreads();
    #pragma unroll
    for (int it = 0; it < 16; ++it) {
      int nl  = w * 16 + it;
      int no  = nt_ + nl;     // output-neuron index
      int k   = kt + lane;    // input index
      int tile = no >> 4, rr = no & 15;
      int ksI  = k >> 5,  qI = (k >> 3) & 3, e = k & 7;
      int idx  = ((tile * 8 + ksI) * 64 + qI * 16 + rr) * 8 + e;
      Wt[mat * 65536 + idx] = (bf16_t)T[lane][nl];
    }
  } else {
    int idx = (blk - (256 + 48)) * 256 + n;  // 64 blocks -> 16384
    xg[idx] = 0.f;
  }
}

// ---------------- main fused g-MLP (layers 2..4) + pair sum ----------------
// one block per (b, i-pair): M = 128 rows (2 i-values x 64 j), N = K = 256.
// Wave tiling: wave owns n-rows [wave*64, wave*64+64) (nt=0..3) and ALL
// 128 m-rows (mt=0..7: h0 for mt<4, h1 for mt>=4).
// Per ks: 4 wf global (1 KB contiguous each, L1-shared across blocks)
//       + 8 hf LDS (lane-contiguous, conflict-free) -> 32 MFMA,
// software-pipelined one ks deep (loads for ks+1 issued before MFMA of ks).
__global__ __launch_bounds__(256, 2) void rn_main_kernel(
    const float* __restrict__ A, const float* __restrict__ C,
    const bf16_t* __restrict__ Wt,
    const float* __restrict__ g2b, const float* __restrict__ g3b,
    const float* __restrict__ g4b,
    float* __restrict__ xg)
{
  __shared__ bf16_t h0[16384];   // 32 KB: [chunk=mt*8+ks][lane][8]
  __shared__ bf16_t h1[16384];   // 32 KB

  int tid  = threadIdx.x;
  int bx0  = blockIdx.x;
  // bijective XCD swizzle (2048 % 8 == 0): 256 consecutive work-units per
  // XCD -> the 32 blocks sharing a batch b stay on one XCD's L2
  int bx   = (bx0 & 7) * 256 + (bx0 >> 3);
  int b    = bx >> 5;          // batch
  int ip   = bx & 31;          // i-pair: i = 2*ip, 2*ip+1
  int lane = tid & 63;
  int wave = tid >> 6;
  int r    = lane & 15;        // 16-dim index within MFMA tile
  int q    = lane >> 4;        // quad: k-run selector / D-row group

  // ---- build h rows into fragment-linear layout ----
  // wave w builds chunks (mt=w, ks=it): thread (q,r) -> m-row j = w*16+r,
  // k-run = it*32+q*8.  LDS writes are lane-contiguous 1 KB per instr.
  {
    const float* Ab = A + (size_t)b * 64 * 256;
    const float* Cr = C + ((size_t)b * 64 + ip * 2) * 256;
    int j = wave * 16 + r;
    #pragma unroll
    for (int it = 0; it < 8; ++it) {
      int k0 = it * 32 + q * 8;
      const float4 a0  = *(const float4*)(Ab + j * 256 + k0);
      const float4 a1  = *(const float4*)(Ab + j * 256 + k0 + 4);
      const float4 c00 = *(const float4*)(Cr + k0);
      const float4 c01 = *(const float4*)(Cr + k0 + 4);
      const float4 c10 = *(const float4*)(Cr + 256 + k0);
      const float4 c11 = *(const float4*)(Cr + 256 + k0 + 4);
      bf16x8 v0, v1;
      v0[0] = (bf16_t)fmaxf(a0.x + c00.x, 0.f);
      v0[1] = (bf16_t)fmaxf(a0.y + c00.y, 0.f);
      v0[2] = (bf16_t)fmaxf(a0.z + c00.z, 0.f);
      v0[3] = (bf16_t)fmaxf(a0.w + c00.w, 0.f);
      v0[4] = (bf16_t)fmaxf(a1.x + c01.x, 0.f);
      v0[5] = (bf16_t)fmaxf(a1.y + c01.y, 0.f);
      v0[6] = (bf16_t)fmaxf(a1.z + c01.z, 0.f);
      v0[7] = (bf16_t)fmaxf(a1.w + c01.w, 0.f);
      v1[0] = (bf16_t)fmaxf(a0.x + c10.x, 0.f);
      v1[1] = (bf16_t)fmaxf(a0.y + c10.y, 0.f);
      v1[2] = (bf16_t)fmaxf(a0.z + c10.z, 0.f);
      v1[3] = (bf16_t)fmaxf(a0.w + c10.w, 0.f);
      v1[4] = (bf16_t)fmaxf(a1.x + c11.x, 0.f);
      v1[5] = (bf16_t)fmaxf(a1.y + c11.y, 0.f);
      v1[6] = (bf16_t)fmaxf(a1.z + c11.z, 0.f);
      v1[7] = (bf16_t)fmaxf(a1.w + c11.w, 0.f);
      int off = ((wave * 8 + it) * 64 + lane) * 8;
      *(bf16x8*)&h0[off] = v0;
      *(bf16x8*)&h1[off] = v1;
    }
  }

  // wave-uniform W base hoisted to SGPR (readfirstlane) for scalar addressing
  int wbase = __builtin_amdgcn_readfirstlane(wave * 16384);

  for (int L = 0; L < 3; ++L) {
    __syncthreads();           // h (build or previous epilogue) visible
    const bf16_t* Wl   = Wt + L * 65536 + wbase;
    const float*  bias = (L == 0) ? g2b : (L == 1) ? g3b : g4b;

    f32x4 acc[4][8];           // [nt][mt]
    #pragma unroll
    for (int nt = 0; nt < 4; ++nt)
      #pragma unroll
      for (int mt = 0; mt < 8; ++mt)
        #pragma unroll
        for (int e = 0; e < 4; ++e) acc[nt][mt][e] = 0.f;

    // ---- software-pipelined ks loop: double-buffered fragments ----
    bf16x8 wfb[2][4], hfb[2][8];

#define LOAD_FRAGS(B, KS)                                                   \
    {                                                                       \
      _Pragma("unroll")                                                     \
      for (int nt = 0; nt < 4; ++nt)                                        \
        wfb[B][nt] = *(const bf16x8*)&Wl[((nt * 8 + (KS)) * 64 + lane) * 8];\
      _Pragma("unroll")                                                     \
      for (int mt = 0; mt < 8; ++mt) {                                      \
        const bf16_t* hb = (mt < 4) ? h0 : h1;                              \
        hfb[B][mt] =                                                        \
            *(const bf16x8*)&hb[(((mt & 3) * 8 + (KS)) * 64 + lane) * 8];   \
      }                                                                     \
    }

    LOAD_FRAGS(0, 0)
    #pragma unroll
    for (int ks = 0; ks < 8; ++ks) {
      int cur = ks & 1;        // folds to a literal under full unroll
      int nxt = cur ^ 1;
      if (ks < 7) LOAD_FRAGS(nxt, ks + 1)   // issue next-ks loads first
      #pragma unroll
      for (int nt = 0; nt < 4; ++nt)
        #pragma unroll
        for (int mt = 0; mt < 8; ++mt)
          acc[nt][mt] = __builtin_amdgcn_mfma_f32_16x16x32_bf16(
              wfb[cur][nt], hfb[cur][mt], acc[nt][mt], 0, 0, 0);
    }
#undef LOAD_FRAGS

    __syncthreads();           // all reads of h done -> safe to overwrite

    if (L < 2) {
      // D value (nt,mt,e): n = wave*64+nt*16+q*4+e (next layer's k),
      // m = mt*16+r (mt<4 -> h0, else h1).  Fragment-linear write-back.
      #pragma unroll
      for (int nt = 0; nt < 4; ++nt) {
        int k0  = wave * 64 + nt * 16 + q * 4;
        float4 bv = *(const float4*)&bias[k0];
        int ks_ = k0 >> 5, rem = k0 & 31;
        int qp  = rem >> 3, e0 = rem & 7;     // e0 in {0,4}
        #pragma unroll
        for (int mt = 0; mt < 8; ++mt) {
          bf16_t* hb = (mt < 4) ? h0 : h1;
          bf16x4 v;
          v[0] = (bf16_t)fmaxf(acc[nt][mt][0] + bv.x, 0.f);
          v[1] = (bf16_t)fmaxf(acc[nt][mt][1] + bv.y, 0.f);
          v[2] = (bf16_t)fmaxf(acc[nt][mt][2] + bv.z, 0.f);
          v[3] = (bf16_t)fmaxf(acc[nt][mt][3] + bv.w, 0.f);
          int off = (((mt & 3) * 8 + ks_) * 64 + qp * 16 + r) * 8 + e0;
          *(bf16x4*)&hb[off] = v;
        }
      }
    } else {
      // last layer: bias+relu fp32, sum over all 128 m-rows
      // (mt in-register, then the 16 r-lanes), atomic to xg.
      #pragma unroll
      for (int nt = 0; nt < 4; ++nt) {
        int k0 = wave * 64 + nt * 16 + q * 4;
        float4 bv = *(const float4*)&bias[k0];
        float p0 = 0.f, p1 = 0.f, p2 = 0.f, p3 = 0.f;
        #pragma unroll
        for (int mt = 0; mt < 8; ++mt) {
          p0 += fmaxf(acc[nt][mt][0] + bv.x, 0.f);
          p1 += fmaxf(acc[nt][mt][1] + bv.y, 0.f);
          p2 += fmaxf(acc[nt][mt][2] + bv.z, 0.f);
          p3 += fmaxf(acc[nt][mt][3] + bv.w, 0.f);
        }
        #pragma unroll
        for (int d = 1; d < 16; d <<= 1) {
          p0 += __shfl_xor(p0, d, 64);
          p1 += __shfl_xor(p1, d, 64);
          p2 += __shfl_xor(p2, d, 64);
          p3 += __shfl_xor(p3, d, 64);
        }
        if (r == 0) {
          int nn = b * 256 + k0;
          atomicAdd(&xg[nn + 0], p0);
          atomicAdd(&xg[nn + 1], p1);
          atomicAdd(&xg[nn + 2], p2);
          atomicAdd(&xg[nn + 3], p3);
        }
      }
    }
  }
}

// ---------------- f-MLP + log_softmax (tiny, fp32) ----------------
__global__ __launch_bounds__(256) void rn_f_kernel(
    const float* __restrict__ xg,
    const float* __restrict__ f1w, const float* __restrict__ f1b,
    const float* __restrict__ f2w, const float* __restrict__ f2b,
    const float* __restrict__ f3w, const float* __restrict__ f3b,
    float* __restrict__ out)
{
  __shared__ float xs[256], t1[256], t2[256], lg[28], lse[1];
  int b = blockIdx.x, tid = threadIdx.x;
  xs[tid] = xg[b * 256 + tid];
  __syncthreads();
  float acc = f1b[tid];
  for (int k = 0; k < 256; ++k) acc += xs[k] * f1w[k * 256 + tid];
  t1[tid] = fmaxf(acc, 0.f);
  __syncthreads();
  acc = f2b[tid];
  for (int k = 0; k < 256; ++k) acc += t1[k] * f2w[k * 256 + tid];
  t2[tid] = fmaxf(acc, 0.f);
  __syncthreads();
  if (tid < 28) {
    float a2 = f3b[tid];
    for (int k = 0; k < 256; ++k) a2 += t2[k] * f3w[k * 28 + tid];
    lg[tid] = a2;
  }
  __syncthreads();
  if (tid == 0) {
    float m = lg[0];
    for (int j = 1; j < 28; ++j) m = fmaxf(m, lg[j]);
    float se = 0.f;
    for (int j = 0; j < 28; ++j) se += expf(lg[j] - m);
    lse[0] = m + logf(se);
  }
  __syncthreads();
  if (tid < 28) out[b * 28 + tid] = lg[tid] - lse[0];
}

// ---------------------------------------------------------------------------
extern "C" void kernel_launch(void* const* d_in, const int* in_sizes, int n_in,
                              void* d_out, int out_size, void* d_ws, size_t ws_size,
                              hipStream_t stream) {
  (void)in_sizes; (void)n_in; (void)out_size; (void)ws_size;
  const float* x   = (const float*)d_in[0];
  const float* qst = (const float*)d_in[1];
  const float* g1w = (const float*)d_in[2];
  const float* g1b = (const float*)d_in[3];
  const float* g2w = (const float*)d_in[4];
  const float* g2b = (const float*)d_in[5];
  const float* g3w = (const float*)d_in[6];
  const float* g3b = (const float*)d_in[7];
  const float* g4w = (const float*)d_in[8];
  const float* g4b = (const float*)d_in[9];
  const float* f1w = (const float*)d_in[10];
  const float* f1b = (const float*)d_in[11];
  const float* f2w = (const float*)d_in[12];
  const float* f2b = (const float*)d_in[13];
  const float* f3w = (const float*)d_in[14];
  const float* f3b = (const float*)d_in[15];
  float* out = (float*)d_out;

  float*  A  = (float*)d_ws;
  float*  C  = A + 4096 * 256;
  bf16_t* Wt = (bf16_t*)(C + 4096 * 256);
  float*  xg = (float*)((char*)Wt + 3 * 65536 * sizeof(bf16_t));

  rn_prep_kernel<<<256 + 48 + 64, 256, 0, stream>>>(
      x, qst, g1w, g1b, g2w, g3w, g4w, A, C, Wt, xg);
  rn_main_kernel<<<2048, 256, 0, stream>>>(A, C, Wt, g2b, g3b, g4b, xg);
  rn_f_kernel<<<64, 256, 0, stream>>>(xg, f1w, f1b, f2w, f2b, f3w, f3b, out);
}